// Round 1
// baseline (99.413 us; speedup 1.0000x reference)
//
#include <hip/hip_runtime.h>
#include <math.h>

#define B_TOT 32768
#define DIM   512
#define NS    100
#define NCOL  101

#define TB    64     // batch rows per block
#define KC    64     // k-chunk
#define PITCH 68     // LDS pitch (floats): mult of 4 (float4 aligned), odd/32 banks -> <=2-way

// Kernel 1: fused logits (sampled GEMM + true gathered dot), writes out[b*101 + c]
__global__ __launch_bounds__(256)
void logits_kernel(const int* __restrict__ label,
                   const float* __restrict__ inputs,
                   const float* __restrict__ weights,
                   const float* __restrict__ biases,
                   const int* __restrict__ sampled_ids,
                   const float* __restrict__ true_q,
                   const float* __restrict__ samp_q,
                   float* __restrict__ out)
{
    __shared__ float A_lds[TB][PITCH];      // [row][k]
    __shared__ float W_lds[128][PITCH];     // [samp col][k], rows >=100 unused
    __shared__ int   s_sid[NS];
    __shared__ int   s_lab[TB];

    const int t  = threadIdx.x;
    const int tx = t & 15;      // col-thread: owns cols c = tx + 16*j, j=0..7
    const int ty = t >> 4;      // row-thread: owns rows ty*4 .. ty*4+3
    const int b0 = blockIdx.x * TB;

    if (t < NS) s_sid[t] = sampled_ids[t];
    if (t < TB) s_lab[t] = label[b0 + t];
    __syncthreads();

    const int r_t = t >> 2;     // true-dot: 4 threads per row
    const int p_t = t & 3;
    const float* wtrue = weights + (long)s_lab[r_t] * DIM;

    float acc[4][8];
    #pragma unroll
    for (int i = 0; i < 4; i++)
        #pragma unroll
        for (int j = 0; j < 8; j++) acc[i][j] = 0.0f;
    float tacc = 0.0f;

    for (int k0 = 0; k0 < DIM; k0 += KC) {
        // --- stage A tile: 64 rows x 64 k, 16 floats per thread ---
        {
            const int r = t >> 2, seg = t & 3;
            const float4* src = (const float4*)(inputs + ((long)(b0 + r) * DIM + k0 + seg * 16));
            float4* dst = (float4*)&A_lds[r][seg * 16];
            #pragma unroll
            for (int q = 0; q < 4; q++) dst[q] = src[q];
        }
        // --- stage W tile: 100 rows x 64 k ---
        for (int idx = t; idx < NS * 16; idx += 256) {
            const int row = idx >> 4, kq = idx & 15;
            *(float4*)&W_lds[row][kq * 4] =
                *(const float4*)(weights + ((long)s_sid[row] * DIM + k0 + kq * 4));
        }
        __syncthreads();

        // --- true-logit partial: 4 threads per row, 16 k each ---
        {
            const float* wr = wtrue + k0 + p_t * 16;
            #pragma unroll
            for (int q = 0; q < 4; q++) {
                const float4 wv = *(const float4*)(wr + q * 4);
                const int kk = p_t * 16 + q * 4;
                tacc = fmaf(A_lds[r_t][kk + 0], wv.x, tacc);
                tacc = fmaf(A_lds[r_t][kk + 1], wv.y, tacc);
                tacc = fmaf(A_lds[r_t][kk + 2], wv.z, tacc);
                tacc = fmaf(A_lds[r_t][kk + 3], wv.w, tacc);
            }
        }

        // --- register-tiled GEMM: 4 rows x 8 cols per thread ---
        #pragma unroll 4
        for (int k = 0; k < KC; k++) {
            float a[4], w[8];
            #pragma unroll
            for (int i = 0; i < 4; i++) a[i] = A_lds[ty * 4 + i][k];
            #pragma unroll
            for (int j = 0; j < 8; j++) w[j] = W_lds[tx + 16 * j][k];
            #pragma unroll
            for (int i = 0; i < 4; i++)
                #pragma unroll
                for (int j = 0; j < 8; j++)
                    acc[i][j] = fmaf(a[i], w[j], acc[i][j]);
        }
        __syncthreads();
    }

    // --- true logit epilogue: reduce 4 partials within wave (lanes t, t^1, t^2) ---
    tacc += __shfl_xor(tacc, 1);
    tacc += __shfl_xor(tacc, 2);
    if (p_t == 0) {
        const int lab = s_lab[r_t];
        out[(long)(b0 + r_t) * NCOL] = tacc + biases[lab] - logf(true_q[b0 + r_t]);
    }

    // --- sampled epilogue ---
    #pragma unroll
    for (int j = 0; j < 8; j++) {
        const int c = tx + 16 * j;
        if (c < NS) {
            const float base = biases[s_sid[c]] - logf(samp_q[c]);
            #pragma unroll
            for (int i = 0; i < 4; i++) {
                const long b = b0 + ty * 4 + i;
                out[b * NCOL + 1 + c] = acc[i][j] + base;
            }
        }
    }
}

// Kernel 2: per-row logsumexp - true_logit; one wave per row, per-block partial sum
__global__ __launch_bounds__(256)
void lse_kernel(const float* __restrict__ logits, float* __restrict__ partial)
{
    const int wave = threadIdx.x >> 6;
    const int lane = threadIdx.x & 63;
    const long b = (long)blockIdx.x * 4 + wave;
    const float* row = logits + b * NCOL;

    float x1 = row[lane];                                    // lane < 64 <= 101 always valid
    float x2 = (lane < NCOL - 64) ? row[lane + 64] : -INFINITY;

    float m = fmaxf(x1, x2);
    #pragma unroll
    for (int o = 32; o > 0; o >>= 1) m = fmaxf(m, __shfl_xor(m, o));

    float s = expf(x1 - m) + ((lane < NCOL - 64) ? expf(x2 - m) : 0.0f);
    #pragma unroll
    for (int o = 32; o > 0; o >>= 1) s += __shfl_xor(s, o);

    const float lse = m + logf(s);
    const float x0 = __shfl(x1, 0);
    const float loss = lse - x0;

    __shared__ float ls[4];
    if (lane == 0) ls[wave] = loss;
    __syncthreads();
    if (threadIdx.x == 0) partial[blockIdx.x] = (ls[0] + ls[1]) + (ls[2] + ls[3]);
}

// Kernel 3: deterministic tree reduce of per-block partials -> mean loss
__global__ __launch_bounds__(256)
void reduce_kernel(const float* __restrict__ partial, int n, float* __restrict__ out_loss)
{
    float s = 0.0f;
    for (int i = threadIdx.x; i < n; i += 256) s += partial[i];
    __shared__ float buf[256];
    buf[threadIdx.x] = s;
    __syncthreads();
    for (int o = 128; o > 0; o >>= 1) {
        if (threadIdx.x < o) buf[threadIdx.x] += buf[threadIdx.x + o];
        __syncthreads();
    }
    if (threadIdx.x == 0) *out_loss = buf[0] * (1.0f / (float)B_TOT);
}

extern "C" void kernel_launch(void* const* d_in, const int* in_sizes, int n_in,
                              void* d_out, int out_size, void* d_ws, size_t ws_size,
                              hipStream_t stream)
{
    const int*   label   = (const int*)d_in[0];
    const float* inputs  = (const float*)d_in[1];
    const float* weights = (const float*)d_in[2];
    const float* biases  = (const float*)d_in[3];
    const int*   sids    = (const int*)d_in[4];
    const float* tq      = (const float*)d_in[5];
    const float* sq      = (const float*)d_in[6];
    float* out = (float*)d_out;
    float* partial = (float*)d_ws;   // 8192 floats

    logits_kernel<<<B_TOT / TB, 256, 0, stream>>>(label, inputs, weights, biases,
                                                  sids, tq, sq, out);
    lse_kernel<<<B_TOT / 4, 256, 0, stream>>>(out, partial);
    reduce_kernel<<<1, 256, 0, stream>>>(partial, B_TOT / 4, out + (long)B_TOT * NCOL);
}

// Round 2
// 40.739 us; speedup vs baseline: 2.4402x; 2.4402x over previous
//
#include <hip/hip_runtime.h>
#include <math.h>

#define B_TOT 32768
#define DIM   512
#define NS    100
#define NCOL  101
#define TB    128              // rows per block (8 waves x 16 rows)
#define NBLK  (B_TOT / TB)     // 256 blocks
#define WPITCH 520             // bf16 elements per W row: 1040B, 16B-aligned, 2-way banks (free)

typedef __attribute__((ext_vector_type(8))) short short8;   // 8 bf16 (4 VGPRs)
typedef __attribute__((ext_vector_type(4))) float f32x4;    // MFMA accumulator

// fp32 -> bf16 round-to-nearest-even, bit form
static __device__ __forceinline__ short f2bf(float f) {
    unsigned u = __builtin_bit_cast(unsigned, f);
    unsigned r = (u + 0x7FFFu + ((u >> 16) & 1u)) >> 16;
    return (short)r;
}

__global__ __launch_bounds__(512)
void fused_kernel(const int* __restrict__ label,
                  const float* __restrict__ inputs,
                  const float* __restrict__ weights,
                  const float* __restrict__ biases,
                  const int* __restrict__ sampled_ids,
                  const float* __restrict__ tq,
                  const float* __restrict__ sq,
                  float* __restrict__ out,
                  float* __restrict__ partial)
{
    __shared__ short W_lds[112 * WPITCH];   // sampled weights, bf16 bits; rows 100-111 unused garbage (masked)
    __shared__ float base_lds[112];         // biases[sid] - log(sq), -inf pad
    __shared__ float tl_lds[TB];            // true logits
    __shared__ float ls_lds[8];             // per-wave loss partials

    const int t = threadIdx.x;

    // ---- stage sampled W as bf16 (once per block), coalesced float4 reads ----
    for (int idx = t; idx < NS * (DIM / 4); idx += 512) {
        const int row = idx >> 7;            // DIM/4 = 128 float4 per row
        const int kq  = (idx & 127) * 4;
        const float4 wv = *(const float4*)(weights + (long)sampled_ids[row] * DIM + kq);
        short4 p = make_short4(f2bf(wv.x), f2bf(wv.y), f2bf(wv.z), f2bf(wv.w));
        *(short4*)&W_lds[row * WPITCH + kq] = p;   // 8B-aligned
    }
    if (t < 112)
        base_lds[t] = (t < NS) ? biases[sampled_ids[t]] - logf(sq[t]) : -INFINITY;

    const int wave = t >> 6;
    const int lane = t & 63;
    const int rit  = lane & 15;              // row within 16-row tile (A-frag + C/D col mapping)
    const int seg  = lane >> 4;              // k-segment 0..3 (8 k each)
    const int absRow = blockIdx.x * TB + wave * 16 + rit;
    const int lab = label[absRow];
    const float* aptr = inputs  + (long)absRow * DIM + seg * 8;
    const float* wtp  = weights + (long)lab    * DIM + seg * 8;

    __syncthreads();

    f32x4 acc[7];
    #pragma unroll
    for (int c = 0; c < 7; c++) acc[c] = (f32x4){0.f, 0.f, 0.f, 0.f};
    float tacc = 0.f;

    // ---- barrier-free K loop: A direct from global (fp32), W-frags from LDS (bf16) ----
    #pragma unroll
    for (int kc = 0; kc < DIM / 32; kc++) {
        const int k0 = kc * 32;
        const float4 a0 = *(const float4*)(aptr + k0);
        const float4 a1 = *(const float4*)(aptr + k0 + 4);
        const float4 w0 = *(const float4*)(wtp + k0);
        const float4 w1 = *(const float4*)(wtp + k0 + 4);

        // true-logit partial in full fp32 (row = rit, k = k0 + seg*8 .. +8)
        tacc = fmaf(a0.x, w0.x, tacc); tacc = fmaf(a0.y, w0.y, tacc);
        tacc = fmaf(a0.z, w0.z, tacc); tacc = fmaf(a0.w, w0.w, tacc);
        tacc = fmaf(a1.x, w1.x, tacc); tacc = fmaf(a1.y, w1.y, tacc);
        tacc = fmaf(a1.z, w1.z, tacc); tacc = fmaf(a1.w, w1.w, tacc);

        // A fragment: lane holds A[rit][k0 + seg*8 + j], j=0..7
        short8 af;
        af[0] = f2bf(a0.x); af[1] = f2bf(a0.y); af[2] = f2bf(a0.z); af[3] = f2bf(a0.w);
        af[4] = f2bf(a1.x); af[5] = f2bf(a1.y); af[6] = f2bf(a1.z); af[7] = f2bf(a1.w);

        const int wko = k0 + seg * 8;
        #pragma unroll
        for (int c = 0; c < 7; c++) {
            const short8 bf = *(const short8*)&W_lds[(c * 16 + rit) * WPITCH + wko];
            acc[c] = __builtin_amdgcn_mfma_f32_16x16x32_bf16(af, bf, acc[c], 0, 0, 0);
        }
    }

    // ---- true logit: reduce 4 k-segments across lane groups ----
    tacc += __shfl_xor(tacc, 16);
    tacc += __shfl_xor(tacc, 32);
    const float tl = tacc + biases[lab] - logf(tq[absRow]);
    if (lane < 16) {
        tl_lds[wave * 16 + lane] = tl;
        out[(long)absRow * NCOL] = tl;
    }
    __syncthreads();

    // ---- fused per-row LSE + loss + sampled-logit writes ----
    // C/D layout: col = lane&15 (rit), row = (lane>>4)*4 + reg
    const int g = lane >> 4;
    float loss_sum = 0.f;
    #pragma unroll
    for (int i = 0; i < 4; i++) {
        const int r = g * 4 + i;
        const long orow = (long)(blockIdx.x * TB + wave * 16 + r) * NCOL;
        const float tlv = tl_lds[wave * 16 + r];
        float v[7];
        float m = tlv;
        #pragma unroll
        for (int c = 0; c < 7; c++) {
            const int col = c * 16 + rit;
            v[c] = (col < NS) ? acc[c][i] + base_lds[col] : -INFINITY;
            m = fmaxf(m, v[c]);
        }
        #pragma unroll
        for (int off = 1; off < 16; off <<= 1) m = fmaxf(m, __shfl_xor(m, off));
        float s = (rit == 0) ? expf(tlv - m) : 0.f;   // count true term once per row
        #pragma unroll
        for (int c = 0; c < 7; c++) s += expf(v[c] - m);   // exp(-inf)=0 for pad cols
        #pragma unroll
        for (int off = 1; off < 16; off <<= 1) s += __shfl_xor(s, off);
        loss_sum += m + logf(s) - tlv;
        #pragma unroll
        for (int c = 0; c < 7; c++) {
            const int col = c * 16 + rit;
            if (col < NS) out[orow + 1 + col] = v[c];
        }
    }
    // loss_sum identical across the 16 lanes of each group; count once per group
    float wl = (rit == 0) ? loss_sum : 0.f;
    wl += __shfl_xor(wl, 16);
    wl += __shfl_xor(wl, 32);
    if (lane == 0) ls_lds[wave] = wl;
    __syncthreads();
    if (t == 0) {
        float bp = 0.f;
        #pragma unroll
        for (int w = 0; w < 8; w++) bp += ls_lds[w];
        partial[blockIdx.x] = bp;
    }
}

// deterministic tree reduce of 256 block partials in double -> mean loss
__global__ __launch_bounds__(256)
void reduce_kernel(const float* __restrict__ partial, float* __restrict__ out_loss)
{
    __shared__ double buf[256];
    buf[threadIdx.x] = (double)partial[threadIdx.x];
    __syncthreads();
    for (int o = 128; o > 0; o >>= 1) {
        if (threadIdx.x < o) buf[threadIdx.x] += buf[threadIdx.x + o];
        __syncthreads();
    }
    if (threadIdx.x == 0) *out_loss = (float)(buf[0] * (1.0 / (double)B_TOT));
}

extern "C" void kernel_launch(void* const* d_in, const int* in_sizes, int n_in,
                              void* d_out, int out_size, void* d_ws, size_t ws_size,
                              hipStream_t stream)
{
    const int*   label   = (const int*)d_in[0];
    const float* inputs  = (const float*)d_in[1];
    const float* weights = (const float*)d_in[2];
    const float* biases  = (const float*)d_in[3];
    const int*   sids    = (const int*)d_in[4];
    const float* tq      = (const float*)d_in[5];
    const float* sq      = (const float*)d_in[6];
    float* out     = (float*)d_out;
    float* partial = (float*)d_ws;   // 256 floats

    fused_kernel<<<NBLK, 512, 0, stream>>>(label, inputs, weights, biases,
                                           sids, tq, sq, out, partial);
    reduce_kernel<<<1, 256, 0, stream>>>(partial, out + (long)B_TOT * NCOL);
}